// Round 4
// baseline (203.942 us; speedup 1.0000x reference)
//
#include <hip/hip_runtime.h>
#include <math.h>

// YOLO loss — R4: persistent waves + double-buffered global_load_lds with
// COUNTED vmcnt (never 0 in steady state).
// Theory: R0-R3 (4 structures) all ~2.8 TB/s effective. R0/R1/R3 are
// VGPR-path concurrency-starved; R2 had DMA depth but burst->vmcnt(0)->exit
// duty cycle. Here each wave loops ~5 tiles: compute tile t from buf A while
// tile t+1's 8 DMAs fly into buf B (s_waitcnt vmcnt(8)), then refill A with
// t+2 after lgkmcnt(0). Scalars prefetch 1 tile ahead in regs. Sustained
// ~80 KB in flight per CU vs ~4 KB before.

#define BLOCK 128
#define WPB 2            // waves per block
#define CPT 64           // cells per tile
#define NBLK 1280        // 5 blocks/CU * 256 CU (LDS 30.7 KB/block -> 5/CU)

// ---- stage one full tile (64 cells * 30 f32 = 480 float4) via DMA: 8 ops ----
#define DMA_TILE(buf, tile) do {                                              \
    const __attribute__((address_space(1))) float4* gp_ =                     \
        (const __attribute__((address_space(1))) float4*)(pred) + (size_t)(tile) * 480; \
    __attribute__((address_space(3))) float4* lp_ =                           \
        (__attribute__((address_space(3))) float4*)(buf);                     \
    _Pragma("unroll")                                                         \
    for (int i_ = 0; i_ < 7; ++i_)                                            \
        __builtin_amdgcn_global_load_lds(                                     \
            (const __attribute__((address_space(1))) void*)(gp_ + lane + i_ * 64), \
            (__attribute__((address_space(3))) void*)(lp_ + i_ * 64), 16, 0, 0); \
    if (lane < 32)                                                            \
        __builtin_amdgcn_global_load_lds(                                     \
            (const __attribute__((address_space(1))) void*)(gp_ + 448 + lane),\
            (__attribute__((address_space(3))) void*)(lp_ + 448), 16, 0, 0);  \
} while (0)

// ---- per-lane scalar prefetch for a tile (7 VMEM ops into regs) ----
#define LOAD_SCAL(tile, mf, tbv, tcv) do {                                    \
    long long c_ = (long long)(tile) * CPT + lane;                            \
    mf  = mask[c_];                                                           \
    tbv = tbox4[c_];                                                          \
    const float4* t4_ = tcls4 + c_ * 5;                                       \
    tcv[0] = t4_[0]; tcv[1] = t4_[1]; tcv[2] = t4_[2];                        \
    tcv[3] = t4_[3]; tcv[4] = t4_[4];                                         \
} while (0)

// ---- declare v0..v14 from a lane's 30 staged floats ----
#define LDSREAD(buf)                                                          \
    const float2* pc2_ = reinterpret_cast<const float2*>((buf) + lane * 30);  \
    float2 v0 = pc2_[0],  v1 = pc2_[1],  v2 = pc2_[2],  v3 = pc2_[3],  v4 = pc2_[4];  \
    float2 v5 = pc2_[5],  v6 = pc2_[6],  v7 = pc2_[7],  v8 = pc2_[8],  v9 = pc2_[9];  \
    float2 v10 = pc2_[10], v11 = pc2_[11], v12 = pc2_[12], v13 = pc2_[13], v14 = pc2_[14];

// floats 0..9: box0=(v0.x,v0.y,v1.x,v1.y, conf v2.x) box1=(v2.y,v3.x,v3.y,v4.x, conf v4.y)
#define CELLMATH(mf, tbv, tcv) do {                                           \
    if (mf) {                                                                 \
        float txc = tbv.x / 14.0f, tyc = tbv.y / 14.0f;                       \
        float t0 = txc - 0.5f * tbv.z, t1 = tyc - 0.5f * tbv.w;               \
        float t2c = txc + 0.5f * tbv.z, t3 = tyc + 0.5f * tbv.w;              \
        float area_t = (t2c - t0) * (t3 - t1);                                \
        float bx[2] = { v0.x, v2.y }, by[2] = { v0.y, v3.x };                 \
        float bw[2] = { v1.x, v3.y }, bh[2] = { v1.y, v4.x };                 \
        float bcf[2] = { v2.x, v4.y };                                        \
        float iou[2];                                                         \
        _Pragma("unroll")                                                     \
        for (int b_ = 0; b_ < 2; ++b_) {                                      \
            float px = bx[b_] / 14.0f, py = by[b_] / 14.0f;                   \
            float q0 = px - 0.5f * bw[b_], q1 = py - 0.5f * bh[b_];           \
            float q2 = px + 0.5f * bw[b_], q3 = py + 0.5f * bh[b_];           \
            float lt0 = fmaxf(t0, q0), lt1 = fmaxf(t1, q1);                   \
            float rb0 = fminf(t2c, q2), rb1 = fminf(t3, q3);                  \
            float ww = fmaxf(rb0 - lt0, 0.f), hh = fmaxf(rb1 - lt1, 0.f);     \
            float inter = ww * hh;                                            \
            float area_p = (q2 - q0) * (q3 - q1);                             \
            iou[b_] = inter / (area_t + area_p - inter);                      \
        }                                                                     \
        int bi = (iou[1] > iou[0]) ? 1 : 0;  /* first-max tie rule */         \
        float dx = bx[bi] - tbv.x, dy = by[bi] - tbv.y;                       \
        float swd = sqrtf(bw[bi]) - sqrtf(tbv.z);                             \
        float shd = sqrtf(bh[bi]) - sqrtf(tbv.w);                             \
        reg = fmaf(5.0f, dx*dx + dy*dy + swd*swd + shd*shd, reg);             \
        float dco = iou[bi] - bcf[bi];                                        \
        cont = fmaf(dco, dco, cont);                                          \
        float d_;                                                             \
        d_ = tcv[0].x - v5.x;  cls = fmaf(d_, d_, cls);                       \
        d_ = tcv[0].y - v5.y;  cls = fmaf(d_, d_, cls);                       \
        d_ = tcv[0].z - v6.x;  cls = fmaf(d_, d_, cls);                       \
        d_ = tcv[0].w - v6.y;  cls = fmaf(d_, d_, cls);                       \
        d_ = tcv[1].x - v7.x;  cls = fmaf(d_, d_, cls);                       \
        d_ = tcv[1].y - v7.y;  cls = fmaf(d_, d_, cls);                       \
        d_ = tcv[1].z - v8.x;  cls = fmaf(d_, d_, cls);                       \
        d_ = tcv[1].w - v8.y;  cls = fmaf(d_, d_, cls);                       \
        d_ = tcv[2].x - v9.x;  cls = fmaf(d_, d_, cls);                       \
        d_ = tcv[2].y - v9.y;  cls = fmaf(d_, d_, cls);                       \
        d_ = tcv[2].z - v10.x; cls = fmaf(d_, d_, cls);                       \
        d_ = tcv[2].w - v10.y; cls = fmaf(d_, d_, cls);                       \
        d_ = tcv[3].x - v11.x; cls = fmaf(d_, d_, cls);                       \
        d_ = tcv[3].y - v11.y; cls = fmaf(d_, d_, cls);                       \
        d_ = tcv[3].z - v12.x; cls = fmaf(d_, d_, cls);                       \
        d_ = tcv[3].w - v12.y; cls = fmaf(d_, d_, cls);                       \
        d_ = tcv[4].x - v13.x; cls = fmaf(d_, d_, cls);                       \
        d_ = tcv[4].y - v13.y; cls = fmaf(d_, d_, cls);                       \
        d_ = tcv[4].z - v14.x; cls = fmaf(d_, d_, cls);                       \
        d_ = tcv[4].w - v14.y; cls = fmaf(d_, d_, cls);                       \
    } else {                                                                  \
        noobj = fmaf(0.5f * v2.x, v2.x, noobj);                               \
        noobj = fmaf(0.5f * v4.y, v4.y, noobj);                               \
    }                                                                         \
} while (0)

__global__ __launch_bounds__(BLOCK) void k_yolo(
    const float*  __restrict__ pred,
    const float4* __restrict__ tbox4,
    const float4* __restrict__ tcls4,
    const int*    __restrict__ mask,
    float4*       __restrict__ partial,
    int n_cells)
{
    __shared__ float sp[WPB][2][CPT * 30];   // 2 waves * 2 bufs * 7.68 KB = 30720 B
    const int tid  = threadIdx.x;
    const int lane = tid & 63;
    const int w    = tid >> 6;

    const int gw = blockIdx.x * WPB + w;      // global wave id
    const int GW = gridDim.x * WPB;           // total waves
    const int F  = n_cells / CPT;             // full tiles
    int m = (F > gw) ? ((F - gw - 1) / GW + 1) : 0;   // this wave's tile count

    float cls = 0.f, noobj = 0.f, reg = 0.f, cont = 0.f;

    float* bufA = &sp[w][0][0];
    float* bufB = &sp[w][1][0];

    int    mf0 = 0, mf1 = 0;
    float4 tb0 = make_float4(0,0,0,0), tb1 = make_float4(0,0,0,0);
    float4 tc0[5], tc1[5];

    if (m > 0) {
        // prologue: T0 DMA + scalars; T1 DMA (order matters for vmcnt counting)
        DMA_TILE(bufA, gw);
        LOAD_SCAL(gw, mf0, tb0, tc0);
        __builtin_amdgcn_sched_barrier(0);
        if (m > 1) DMA_TILE(bufB, (long long)gw + GW);

        int k = 0;
        long long tcur = gw;
        while (true) {
            { // ---- tile T[k] from bufA, scalars set 0 ----
                if (k + 1 < m) asm volatile("s_waitcnt vmcnt(8)" ::: "memory");
                else           asm volatile("s_waitcnt vmcnt(0)" ::: "memory");
                __builtin_amdgcn_sched_barrier(0);
                LDSREAD(bufA)
                asm volatile("s_waitcnt lgkmcnt(0)" ::: "memory");
                __builtin_amdgcn_sched_barrier(0);
                if (k + 1 < m) LOAD_SCAL(tcur + GW, mf1, tb1, tc1);
                __builtin_amdgcn_sched_barrier(0);
                if (k + 2 < m) DMA_TILE(bufA, tcur + 2 * GW);
                CELLMATH(mf0, tb0, tc0);
            }
            ++k; tcur += GW;
            if (k == m) break;
            { // ---- tile T[k] from bufB, scalars set 1 ----
                if (k + 1 < m) asm volatile("s_waitcnt vmcnt(8)" ::: "memory");
                else           asm volatile("s_waitcnt vmcnt(0)" ::: "memory");
                __builtin_amdgcn_sched_barrier(0);
                LDSREAD(bufB)
                asm volatile("s_waitcnt lgkmcnt(0)" ::: "memory");
                __builtin_amdgcn_sched_barrier(0);
                if (k + 1 < m) LOAD_SCAL(tcur + GW, mf0, tb0, tc0);
                __builtin_amdgcn_sched_barrier(0);
                if (k + 2 < m) DMA_TILE(bufB, tcur + 2 * GW);
                CELLMATH(mf1, tb1, tc1);
            }
            ++k; tcur += GW;
            if (k == m) break;
        }
    }

    // ---- generic tail: partial tile handled by global wave 0 (dead for bench shape) ----
    int rem = n_cells - F * CPT;
    if (rem > 0 && gw == 0) {
        long long cell0 = (long long)F * CPT;
        const float* gsrc = pred + cell0 * 30;
        for (int kk = lane; kk < rem * 30; kk += 64) bufA[kk] = gsrc[kk];
        int    mfp = 0;
        float4 tbp = make_float4(0,0,0,0);
        float4 tcp[5];
        if (lane < rem) LOAD_SCAL(F, mfp, tbp, tcp);   // lane offset inside macro
        asm volatile("s_waitcnt vmcnt(0) lgkmcnt(0)" ::: "memory");
        __builtin_amdgcn_sched_barrier(0);
        if (lane < rem) {
            LDSREAD(bufA)
            CELLMATH(mfp, tbp, tcp);
        }
    }

    // ---- wave shuffle reduce, then block reduce, store partial ----
    #pragma unroll
    for (int off = 32; off; off >>= 1) {
        cls   += __shfl_down(cls,   off, 64);
        noobj += __shfl_down(noobj, off, 64);
        reg   += __shfl_down(reg,   off, 64);
        cont  += __shfl_down(cont,  off, 64);
    }
    __shared__ float4 swr[WPB];
    if (lane == 0) swr[w] = make_float4(cls, noobj, reg, cont);
    __syncthreads();
    if (tid == 0) {
        float4 a = swr[0];
        #pragma unroll
        for (int i = 1; i < WPB; ++i) {
            float4 b = swr[i];
            a.x += b.x; a.y += b.y; a.z += b.z; a.w += b.w;
        }
        partial[blockIdx.x] = a;
    }
}

__global__ __launch_bounds__(256) void k_final(
    const float4* __restrict__ partial, int nblocks,
    float* __restrict__ out, float invN)
{
    float4 acc = make_float4(0.f, 0.f, 0.f, 0.f);
    for (int b = threadIdx.x; b < nblocks; b += 256) {
        float4 v = partial[b];
        acc.x += v.x; acc.y += v.y; acc.z += v.z; acc.w += v.w;
    }
    #pragma unroll
    for (int off = 32; off; off >>= 1) {
        acc.x += __shfl_down(acc.x, off, 64);
        acc.y += __shfl_down(acc.y, off, 64);
        acc.z += __shfl_down(acc.z, off, 64);
        acc.w += __shfl_down(acc.w, off, 64);
    }
    __shared__ float4 sw[4];
    int lane = threadIdx.x & 63, w = threadIdx.x >> 6;
    if (lane == 0) sw[w] = acc;
    __syncthreads();
    if (threadIdx.x == 0) {
        float cls = 0.f, noobj = 0.f, reg = 0.f, cont = 0.f;
        #pragma unroll
        for (int i = 0; i < 4; ++i) {
            cls += sw[i].x; noobj += sw[i].y; reg += sw[i].z; cont += sw[i].w;
        }
        out[0] = (cls + noobj + reg + cont) * invN;
        out[1] = reg;
        out[2] = cont;
        out[3] = noobj;
        out[4] = cls;
    }
}

extern "C" void kernel_launch(void* const* d_in, const int* in_sizes, int n_in,
                              void* d_out, int out_size, void* d_ws, size_t ws_size,
                              hipStream_t stream) {
    const float*  pred  = (const float*)d_in[0];   // (N,14,14,30) f32
    const float4* tbox4 = (const float4*)d_in[1];  // (N,14,14,4)  f32
    const float4* tcls4 = (const float4*)d_in[2];  // (N,14,14,20) f32
    const int*    mask  = (const int*)d_in[3];     // (N,14,14)    int32
    float* out = (float*)d_out;
    float4* partial = (float4*)d_ws;

    int n_cells = in_sizes[3];
    int N = in_sizes[0] / (14 * 14 * 30);

    hipLaunchKernelGGL(k_yolo, dim3(NBLK), dim3(BLOCK), 0, stream,
                       pred, tbox4, tcls4, mask, partial, n_cells);
    hipLaunchKernelGGL(k_final, dim3(1), dim3(256), 0, stream,
                       partial, NBLK, out, 1.0f / (float)N);
}